// Round 8
// baseline (126.632 us; speedup 1.0000x reference)
//
#include <hip/hip_runtime.h>
#include <math.h>

#define BN 1024
#define DN 256
#define HN 256
#define KN 8
#define SP 260  // padded row stride (floats) for per-row LDS vectors
#define PS ((size_t)BN * BN)  // partial-plane stride (floats)
typedef unsigned long long u64;

// ---------------- Kernel A: pairwise squared-distance PARTIALS ----------------
// D-split for occupancy: block (bx,by,bz) computes the 64x64 tile's partial
// d^2 over d-chunk bz*64..+63. Grid (16,16,4) = 1024 blocks = 4 blocks/CU
// = 4 waves/SIMD (vs 1 before): TLP hides LDS latency that the 1-wave/SIMD
// version exposed (~38us vs ~7us VALU floor). LDS 32KB/block (4x32=128<=160).
// Swizzle p = s ^ ((row>>2)&7 ^ ((row&3)<<1)): A-reads conflict-free,
// B-reads 2-way (free per m136), staging writes 8-way on 8 instrs (minor).
__global__ __launch_bounds__(256) void k_dist2(const float* __restrict__ x,
                                               float* __restrict__ part) {
  __shared__ float4 xi4[64][16];
  __shared__ float4 xj4[64][16];
  const int tid = threadIdx.x;
  const int tx = tid & 15, ty = tid >> 4;
  const int i0 = blockIdx.y << 6, j0 = blockIdx.x << 6;
  const int d0 = blockIdx.z << 6;

#pragma unroll
  for (int q = 0; q < 4; ++q) {
    int f = (q << 8) + tid;  // 0..1023 float4 slot
    int row = f >> 4, s = f & 15;
    int p = s ^ (((row >> 2) & 7) ^ ((row & 3) << 1));
    xi4[row][p] = *reinterpret_cast<const float4*>(
        x + (size_t)(i0 + row) * DN + d0 + (s << 2));
    xj4[row][p] = *reinterpret_cast<const float4*>(
        x + (size_t)(j0 + row) * DN + d0 + (s << 2));
  }
  __syncthreads();

  float acc[4][4];
#pragma unroll
  for (int m = 0; m < 4; ++m)
#pragma unroll
    for (int n = 0; n < 4; ++n) acc[m][n] = 0.f;

  const int pia = ty & 7, pib = tx & 7;
#pragma unroll 4
  for (int g = 0; g < 16; ++g) {
    float4 A[4], Bv[4];
#pragma unroll
    for (int m = 0; m < 4; ++m) A[m] = xi4[(ty << 2) + m][g ^ pia ^ (m << 1)];
#pragma unroll
    for (int n = 0; n < 4; ++n) Bv[n] = xj4[(tx << 2) + n][g ^ pib ^ (n << 1)];
#pragma unroll
    for (int m = 0; m < 4; ++m)
#pragma unroll
      for (int n = 0; n < 4; ++n) {
        float t0 = A[m].x - Bv[n].x;
        float t1 = A[m].y - Bv[n].y;
        float t2 = A[m].z - Bv[n].z;
        float t3 = A[m].w - Bv[n].w;
        acc[m][n] = fmaf(t0, t0, acc[m][n]);
        acc[m][n] = fmaf(t1, t1, acc[m][n]);
        acc[m][n] = fmaf(t2, t2, acc[m][n]);
        acc[m][n] = fmaf(t3, t3, acc[m][n]);
      }
  }

  float* plane = part + (size_t)blockIdx.z * PS;
#pragma unroll
  for (int m = 0; m < 4; ++m) {
    float4 o;
    o.x = acc[m][0]; o.y = acc[m][1]; o.z = acc[m][2]; o.w = acc[m][3];
    *reinterpret_cast<float4*>(plane + (size_t)(i0 + (ty << 2) + m) * BN +
                               j0 + (tx << 2)) = o;
  }
}

// ---------- Kernel B: fused top-K + epilogue (strip-dot matvecs) ----------
// Identical to R7 except phase 1 sums the 4 d-chunk partials in fixed order
// (p0+p1)+(p2+p3) sequential -> deterministic, same ~1e-4 error scale as
// the passing direct sum. Key = (f32bits<<32)|j matches lax.top_k ties.
__global__ __launch_bounds__(256) void k_sel_row(
    const float* __restrict__ x, const float* __restrict__ W_diff,
    const float* __restrict__ b_diff, const float* __restrict__ W_tau,
    const float* __restrict__ b_tau, const float* __restrict__ W_agg,
    const float* __restrict__ b_agg, const float* __restrict__ W_res,
    const float* __restrict__ b_res, const float* __restrict__ gamma,
    const float* __restrict__ beta, const float* __restrict__ part,
    float* __restrict__ out) {
  const int tid = threadIdx.x;
  const int lane = tid & 63, wv = tid >> 6;
  const int r0 = blockIdx.x << 2;
  __shared__ float s_x[4 * SP];
  __shared__ float s_s[4 * SP];
  __shared__ float s_hk[4 * SP];
  __shared__ float s_y[4 * SP];
  __shared__ float s_tau[4];
  __shared__ float s_mu[4], s_rs[4];
  __shared__ int s_idx[4 * KN];

#pragma unroll
  for (int r = 0; r < 4; ++r)
    s_x[r * SP + tid] = x[(size_t)(r0 + r) * DN + tid];

  // ---- phase 1: top-8 for row r0+wv (one wave per row, no barriers) ----
  {
    const int row = r0 + wv;
    const float* base = part + (size_t)row * BN;
    u64 key[16];
#pragma unroll
    for (int q = 0; q < 4; ++q) {
      int j = (q << 8) + (lane << 2);
      float4 v0 = *reinterpret_cast<const float4*>(base + j);
      float4 v1 = *reinterpret_cast<const float4*>(base + PS + j);
      float4 v2 = *reinterpret_cast<const float4*>(base + 2 * PS + j);
      float4 v3 = *reinterpret_cast<const float4*>(base + 3 * PS + j);
      float dx = v0.x + v1.x + v2.x + v3.x;
      float dy = v0.y + v1.y + v2.y + v3.y;
      float dz = v0.z + v1.z + v2.z + v3.z;
      float dw = v0.w + v1.w + v2.w + v3.w;
      key[q * 4 + 0] = ((u64)__float_as_uint(dx) << 32) | (unsigned)(j + 0);
      key[q * 4 + 1] = ((u64)__float_as_uint(dy) << 32) | (unsigned)(j + 1);
      key[q * 4 + 2] = ((u64)__float_as_uint(dz) << 32) | (unsigned)(j + 2);
      key[q * 4 + 3] = ((u64)__float_as_uint(dw) << 32) | (unsigned)(j + 3);
    }
    for (int r = 0; r < KN; ++r) {
      u64 m = key[0];
#pragma unroll
      for (int l = 1; l < 16; ++l) m = key[l] < m ? key[l] : m;
#pragma unroll
      for (int off = 32; off > 0; off >>= 1) {
        u64 o = __shfl_xor(m, off);
        m = o < m ? o : m;
      }
      if (lane == 0) s_idx[wv * KN + r] = (int)(unsigned)(m & 0xffffffffull);
#pragma unroll
      for (int l = 0; l < 16; ++l)
        if (key[l] == m) key[l] = ~0ull;
    }
  }
  __syncthreads();  // s_idx + s_x visible

  // ---- |diff| sums over the K neighbors ----
#pragma unroll
  for (int r = 0; r < 4; ++r) {
    float xv = s_x[r * SP + tid];
    float s = 0.f;
#pragma unroll
    for (int k = 0; k < KN; ++k) {
      int j = s_idx[r * KN + k];
      s += fabsf(xv - x[(size_t)j * DN + tid]);
    }
    s_s[r * SP + tid] = s;
  }
  // ---- tau: wave wv reduces row wv ----
  {
    float p = 0.f;
#pragma unroll
    for (int q = 0; q < DN / 64; ++q) {
      int d = lane + (q << 6);
      p += s_x[wv * SP + d] * W_tau[d];
    }
#pragma unroll
    for (int off = 32; off > 0; off >>= 1) p += __shfl_down(p, off);
    if (lane == 0) {
      float z = p + b_tau[0];
      float sp = z > 0.f ? z + log1pf(expf(-z)) : log1pf(expf(z));
      s_tau[wv] = fmaxf(sp, 0.01f) + 1.0f;
    }
  }
  __syncthreads();  // covers s_s and s_tau

  // ---- matvec passes: coalesced strip-dot ----
  auto ldchunk = [&](float4* g, const float* W, int hb) {
#pragma unroll
    for (int j = 0; j < 8; ++j)
      g[j] = *reinterpret_cast<const float4*>(W + ((size_t)(hb + j) << 8) +
                                              (lane << 2));
  };
  auto dotchunk = [&](const float4* w, const float4* sv) -> float {
    float v32[32];
#pragma unroll
    for (int j = 0; j < 8; ++j)
#pragma unroll
      for (int r = 0; r < 4; ++r) {
        float a = w[j].x * sv[r].x;
        a = fmaf(w[j].y, sv[r].y, a);
        a = fmaf(w[j].z, sv[r].z, a);
        a = fmaf(w[j].w, sv[r].w, a);
        v32[j * 4 + r] = a;
      }
    float v16[16], v8[8], v4[4], v2[2], vf;
#pragma unroll
    for (int m = 0; m < 16; ++m) {
      float keep = (lane & 1) ? v32[2 * m + 1] : v32[2 * m];
      float send = (lane & 1) ? v32[2 * m] : v32[2 * m + 1];
      v16[m] = keep + __shfl_xor(send, 1);
    }
#pragma unroll
    for (int m = 0; m < 8; ++m) {
      float keep = (lane & 2) ? v16[2 * m + 1] : v16[2 * m];
      float send = (lane & 2) ? v16[2 * m] : v16[2 * m + 1];
      v8[m] = keep + __shfl_xor(send, 2);
    }
#pragma unroll
    for (int m = 0; m < 4; ++m) {
      float keep = (lane & 4) ? v8[2 * m + 1] : v8[2 * m];
      float send = (lane & 4) ? v8[2 * m] : v8[2 * m + 1];
      v4[m] = keep + __shfl_xor(send, 4);
    }
#pragma unroll
    for (int m = 0; m < 2; ++m) {
      float keep = (lane & 8) ? v4[2 * m + 1] : v4[2 * m];
      float send = (lane & 8) ? v4[2 * m] : v4[2 * m + 1];
      v2[m] = keep + __shfl_xor(send, 8);
    }
    {
      float keep = (lane & 16) ? v2[1] : v2[0];
      float send = (lane & 16) ? v2[0] : v2[1];
      vf = keep + __shfl_xor(send, 16);
    }
    vf += __shfl_xor(vf, 32);
    return vf;
  };

  const int oj = (lane & 31) >> 2;
  const int orr = lane & 3;

  // pass A: W_diff -> s_hk
  {
    float4 sA[4];
#pragma unroll
    for (int r = 0; r < 4; ++r)
      sA[r] = *reinterpret_cast<const float4*>(&s_s[r * SP + (lane << 2)]);
    float4 g[8];
    ldchunk(g, W_diff, wv << 6);
#pragma unroll
    for (int s = 0; s < 8; ++s) {
      float4 w[8];
#pragma unroll
      for (int j = 0; j < 8; ++j) w[j] = g[j];
      if (s < 7) ldchunk(g, W_diff, (wv << 6) + ((s + 1) << 3));
      float vf = dotchunk(w, sA);
      int h = (wv << 6) + (s << 3) + oj;
      s_hk[orr * SP + h] = (vf * 0.125f + b_diff[h]) / s_tau[orr];
    }
  }
  __syncthreads();

  // pass B: W_agg (on h_k) then W_res (on x); relu + residual -> s_y
  {
    float4 sH[4], sX[4];
#pragma unroll
    for (int r = 0; r < 4; ++r) {
      sH[r] = *reinterpret_cast<const float4*>(&s_hk[r * SP + (lane << 2)]);
      sX[r] = *reinterpret_cast<const float4*>(&s_x[r * SP + (lane << 2)]);
    }
    float aggv[8];
    float4 g[8];
    ldchunk(g, W_agg, wv << 6);
#pragma unroll
    for (int s = 0; s < 8; ++s) {
      float4 w[8];
#pragma unroll
      for (int j = 0; j < 8; ++j) w[j] = g[j];
      if (s < 7) ldchunk(g, W_agg, (wv << 6) + ((s + 1) << 3));
      aggv[s] = dotchunk(w, sH);
    }
    ldchunk(g, W_res, wv << 6);
#pragma unroll
    for (int s = 0; s < 8; ++s) {
      float4 w[8];
#pragma unroll
      for (int j = 0; j < 8; ++j) w[j] = g[j];
      if (s < 7) ldchunk(g, W_res, (wv << 6) + ((s + 1) << 3));
      float resv = dotchunk(w, sX);
      int h = (wv << 6) + (s << 3) + oj;
      float yv = fmaxf(aggv[s] + b_agg[h], 0.f) + resv + b_res[h];
      s_y[orr * SP + h] = yv;
    }
  }
  __syncthreads();

  // ---- LayerNorm: wave wv reduces row wv ----
  {
    float sum = 0.f, sq = 0.f;
#pragma unroll
    for (int q = 0; q < HN / 64; ++q) {
      float v = s_y[wv * SP + lane + (q << 6)];
      sum += v;
      sq += v * v;
    }
#pragma unroll
    for (int off = 32; off > 0; off >>= 1) {
      sum += __shfl_down(sum, off);
      sq += __shfl_down(sq, off);
    }
    if (lane == 0) {
      float mu = sum * (1.f / HN);
      float var = sq * (1.f / HN) - mu * mu;
      s_mu[wv] = mu;
      s_rs[wv] = 1.f / sqrtf(var + 1e-5f);
    }
  }
  __syncthreads();

  float g = gamma[tid], be = beta[tid];
#pragma unroll
  for (int r = 0; r < 4; ++r) {
    out[(size_t)(r0 + r) * HN + tid] =
        (s_y[r * SP + tid] - s_mu[r]) * s_rs[r] * g + be;
  }
}

extern "C" void kernel_launch(void* const* d_in, const int* in_sizes, int n_in,
                              void* d_out, int out_size, void* d_ws,
                              size_t ws_size, hipStream_t stream) {
  const float* x = (const float*)d_in[0];
  const float* W_diff = (const float*)d_in[1];
  const float* b_diff = (const float*)d_in[2];
  const float* W_tau = (const float*)d_in[3];
  const float* b_tau = (const float*)d_in[4];
  const float* W_agg = (const float*)d_in[5];
  const float* b_agg = (const float*)d_in[6];
  const float* W_res = (const float*)d_in[7];
  const float* b_res = (const float*)d_in[8];
  const float* gamma = (const float*)d_in[9];
  const float* beta = (const float*)d_in[10];
  float* out = (float*)d_out;

  float* part = (float*)d_ws;  // 4 planes x 4 MB = 16 MB (ws is ~256 MB)

  dim3 gA(BN / 64, BN / 64, 4);
  k_dist2<<<gA, 256, 0, stream>>>(x, part);
  k_sel_row<<<BN / 4, 256, 0, stream>>>(x, W_diff, b_diff, W_tau, b_tau,
                                        W_agg, b_agg, W_res, b_res, gamma,
                                        beta, part, out);
}